// Round 15
// baseline (1906.954 us; speedup 1.0000x reference)
//
#include <hip/hip_runtime.h>
#include <hip/hip_bf16.h>
#include <math.h>

#define BB 16
#define TT 256
#define DD 512
#define EE 512
#define VV 32000
#define G4 2048   // 4*D
#define NWORK 128
#define NTILES (16 * 2 * 250)   // 16 t-chunks x 2 b-groups x 250 n-tiles

typedef __attribute__((ext_vector_type(4))) float f32x4;
typedef __attribute__((ext_vector_type(8))) short bf16x8;
typedef __attribute__((ext_vector_type(4))) unsigned u32x4;

union lf_u { u32x4 q; bf16x8 v; };

#define SENTMASK32 0x40004000u               // bit14 per bf16 halfword
#define SENTMASK64 0x4000400040004000ULL

__device__ __forceinline__ unsigned short f2bf(float x) {
    unsigned u = __float_as_uint(x);
    unsigned r = (u + 0x7FFFu + ((u >> 16) & 1u)) >> 16;
    return (unsigned short)r;
}

__device__ __forceinline__ float sigmoidf_(float x) { return 1.0f / (1.0f + expf(-x)); }

// ---------------- fused prefix: gather + Wih0x cvt + enc_term ----------------
__global__ __launch_bounds__(256) void k_prep(
        const int* __restrict__ tok, const float* __restrict__ embed,
        unsigned short* __restrict__ Xb,
        const float* __restrict__ Wih0, unsigned short* __restrict__ Wih0xb,
        const float* __restrict__ enc, const float* __restrict__ bih0,
        const float* __restrict__ bhh0, float* __restrict__ et) {
    __shared__ float es[EE];
    const int blk = blockIdx.x;
    const int tid = threadIdx.x;
    if (blk < BB * TT) {
        int tk = tok[blk];
        const float* src = embed + (size_t)tk * DD;
        int i = tid * 2;
        float vx = 0.f, vy = 0.f;
        if (tk != 0) { float2 v = *(const float2*)&src[i]; vx = v.x; vy = v.y; }
        ushort2 o; o.x = f2bf(vx); o.y = f2bf(vy);
        *(ushort2*)&Xb[(size_t)blk * DD + i] = o;
    } else if (blk < BB * TT + 1024) {
        int i = (blk - BB * TT) * 256 + tid;
        int j = i >> 7;
        int k4 = (i & 127) << 2;
        float4 v = *(const float4*)&Wih0[(size_t)j * (EE + DD) + k4];
        ushort4 o; o.x = f2bf(v.x); o.y = f2bf(v.y); o.z = f2bf(v.z); o.w = f2bf(v.w);
        *(ushort4*)&Wih0xb[(size_t)j * DD + k4] = o;
    } else {
        int bidx = blk - (BB * TT + 1024);
        int b = bidx >> 3, jc = bidx & 7;
        int lane = tid & 63, w = tid >> 6;
        if (tid < EE / 4) *(float4*)&es[tid * 4] = *(const float4*)&enc[b * EE + tid * 4];
        __syncthreads();
        float4 e0 = *(const float4*)&es[lane * 4];
        float4 e1 = *(const float4*)&es[256 + lane * 4];
        for (int o = 0; o < 64; ++o) {
            int j = jc * 256 + w * 64 + o;
            const float4* Wr = (const float4*)&Wih0[(size_t)j * (EE + DD) + DD];
            float4 w0 = Wr[lane], w1 = Wr[64 + lane];
            float s = w0.x*e0.x + w0.y*e0.y + w0.z*e0.z + w0.w*e0.w
                    + w1.x*e1.x + w1.y*e1.y + w1.z*e1.z + w1.w*e1.w;
            #pragma unroll
            for (int off = 32; off; off >>= 1) s += __shfl_xor(s, off);
            if (lane == 0) et[b * G4 + j] = s + bih0[j] + bhh0[j];
        }
    }
}

// ---------------- bf16 MFMA GEMM (Gx pre-GEMM only), C = A@B^T + enc_term ----------------
__global__ __launch_bounds__(256) void k_gemm0(
        const unsigned short* __restrict__ A, const unsigned short* __restrict__ Bm,
        float* __restrict__ C, const float* __restrict__ extra,
        int M, int N, int K) {
    __shared__ __align__(16) unsigned short Alds[128 * 32];
    __shared__ __align__(16) unsigned short Blds[128 * 32];
    int tid = threadIdx.x, lane = tid & 63, w = tid >> 6;
    int wr = w >> 1, wc = w & 1;
    int nwgx = gridDim.x;
    int nwg = nwgx * gridDim.y;
    int lin = blockIdx.y * nwgx + blockIdx.x;
    int cpx = nwg >> 3;
    lin = (lin & 7) * cpx + (lin >> 3);
    int m0 = (lin % nwgx) * 128, n0 = (lin / nwgx) * 128;
    f32x4 acc[4][4];
    #pragma unroll
    for (int i = 0; i < 4; i++)
        #pragma unroll
        for (int j = 0; j < 4; j++) acc[i][j] = (f32x4)0.f;

    const char* Abase = (const char*)A;
    const char* Bbase = (const char*)Bm;
    for (int ks = 0; ks < K; ks += 32) {
        #pragma unroll
        for (int c = 0; c < 2; ++c) {
            int f = (tid + c * 256) * 16;
            int row = f >> 6;
            int inb = f & 63;
            const char* gA = Abase + (((size_t)(m0 + row) * K + ks) * 2 + inb);
            __builtin_amdgcn_global_load_lds(
                (const __attribute__((address_space(1))) void*)gA,
                (__attribute__((address_space(3))) void*)((char*)Alds + f), 16, 0, 0);
            const char* gB = Bbase + (((size_t)(n0 + row) * K + ks) * 2 + inb);
            __builtin_amdgcn_global_load_lds(
                (const __attribute__((address_space(1))) void*)gB,
                (__attribute__((address_space(3))) void*)((char*)Blds + f), 16, 0, 0);
        }
        __syncthreads();
        bf16x8 af[4], bfr[4];
        int r = lane & 15, ko = (lane >> 4) * 8;
        #pragma unroll
        for (int mi = 0; mi < 4; ++mi)
            af[mi] = *(const bf16x8*)&Alds[(wr * 64 + mi * 16 + r) * 32 + ko];
        #pragma unroll
        for (int ni = 0; ni < 4; ++ni)
            bfr[ni] = *(const bf16x8*)&Blds[(wc * 64 + ni * 16 + r) * 32 + ko];
        #pragma unroll
        for (int mi = 0; mi < 4; ++mi)
            #pragma unroll
            for (int ni = 0; ni < 4; ++ni)
                acc[mi][ni] = __builtin_amdgcn_mfma_f32_16x16x32_bf16(af[mi], bfr[ni], acc[mi][ni], 0, 0, 0);
        __syncthreads();
    }
    int cr = (lane >> 4) * 4, cc = lane & 15;
    #pragma unroll
    for (int mi = 0; mi < 4; ++mi) {
        #pragma unroll
        for (int ni = 0; ni < 4; ++ni) {
            int col = n0 + wc * 64 + ni * 16 + cc;
            #pragma unroll
            for (int rr = 0; rr < 4; ++rr) {
                int rowg = m0 + wr * 64 + mi * 16 + cr + rr;
                C[(size_t)rowg * N + col] = acc[mi][ni][rr] + extra[(rowg >> 8) * G4 + col];
            }
        }
    }
}

// ---------------- fully-coherent (sc0 sc1) batched 16x16B load ----------------
__device__ __forceinline__ void load16sc(const void* base, lf_u* o) {
    asm volatile(
        "global_load_dwordx4 %0, %16, off sc0 sc1\n\t"
        "global_load_dwordx4 %1, %16, off offset:64 sc0 sc1\n\t"
        "global_load_dwordx4 %2, %16, off offset:128 sc0 sc1\n\t"
        "global_load_dwordx4 %3, %16, off offset:192 sc0 sc1\n\t"
        "global_load_dwordx4 %4, %16, off offset:256 sc0 sc1\n\t"
        "global_load_dwordx4 %5, %16, off offset:320 sc0 sc1\n\t"
        "global_load_dwordx4 %6, %16, off offset:384 sc0 sc1\n\t"
        "global_load_dwordx4 %7, %16, off offset:448 sc0 sc1\n\t"
        "global_load_dwordx4 %8, %16, off offset:512 sc0 sc1\n\t"
        "global_load_dwordx4 %9, %16, off offset:576 sc0 sc1\n\t"
        "global_load_dwordx4 %10, %16, off offset:640 sc0 sc1\n\t"
        "global_load_dwordx4 %11, %16, off offset:704 sc0 sc1\n\t"
        "global_load_dwordx4 %12, %16, off offset:768 sc0 sc1\n\t"
        "global_load_dwordx4 %13, %16, off offset:832 sc0 sc1\n\t"
        "global_load_dwordx4 %14, %16, off offset:896 sc0 sc1\n\t"
        "global_load_dwordx4 %15, %16, off offset:960 sc0 sc1\n\t"
        "s_waitcnt vmcnt(0)"
        : "=&v"(o[0].q), "=&v"(o[1].q), "=&v"(o[2].q), "=&v"(o[3].q),
          "=&v"(o[4].q), "=&v"(o[5].q), "=&v"(o[6].q), "=&v"(o[7].q),
          "=&v"(o[8].q), "=&v"(o[9].q), "=&v"(o[10].q), "=&v"(o[11].q),
          "=&v"(o[12].q), "=&v"(o[13].q), "=&v"(o[14].q), "=&v"(o[15].q)
        : "v"(base)
        : "memory");
}

// sentinel poll with backoff
__device__ __forceinline__ void poll16sc(const void* base, lf_u* o) {
    for (;;) {
        load16sc(base, o);
        unsigned bad = 0;
        #pragma unroll
        for (int kt = 0; kt < 16; ++kt)
            bad |= (o[kt].q.x | o[kt].q.y | o[kt].q.z | o[kt].q.w);
        if (!__any((bad & SENTMASK32) != 0)) return;
        __builtin_amdgcn_s_sleep(1);
    }
}

__device__ __forceinline__ void store8sc(void* addr, unsigned long long v) {
    asm volatile("global_store_dwordx2 %0, %1, off sc0 sc1"
                 :: "v"(addr), "v"(v) : "memory");
}

__device__ __forceinline__ void store16sc(void* addr, unsigned long long lo, unsigned long long hi) {
    u32x4 v;
    v.x = (unsigned)lo; v.y = (unsigned)(lo >> 32);
    v.z = (unsigned)hi; v.w = (unsigned)(hi >> 32);
    asm volatile("global_store_dwordx4 %0, %1, off sc0 sc1"
                 :: "v"(addr), "v"(v) : "memory");
}

// ---------------- mega kernel: persistent recurrence + observer flags + out-GEMM ----------------
// 256 blocks x 256 threads, 1 block/CU (co-resident).
// Blocks 0..15:  layer 0, d-slice of 32 (16 producers: halved fan-in on the critical chain).
//                128KB weights in LDS (8 B-tiles x 16 kt), 128 MFMA/step, 16B/lane h-store.
// Blocks 16..47: layer 1, d-slice of 16 (wave 0 = r11 loop; wave 1 = observer publishing ep1).
// Blocks 48..63: exit. Blocks 64..191: out-GEMM workers. Rest exit.
// Protocol unchanged: sentinel (bit14) data-as-flag, sc0 sc1 coherent path, no ordering deps.
__global__ __launch_bounds__(256) void k_mega(
        const float* __restrict__ Gx,
        const float* __restrict__ Whh0,
        const float* __restrict__ Wih1, const float* __restrict__ Whh1,
        const float* __restrict__ bih1, const float* __restrict__ bhh1,
        unsigned short* h0hist, unsigned short* outsb,
        const unsigned short* zbuf,
        const float* __restrict__ Wout, unsigned short* Woutb,
        const float* __restrict__ bout, float* __restrict__ out,
        int* ep1, int* tick, int* wdone) {
    __shared__ __align__(16) unsigned char smem[4 * 32 * 512 * 2 + 1024];
    __shared__ int idSh;
    const int bid = blockIdx.x;

    if (bid < 48) {
        // ================= recurrence role =================
        unsigned short* wfrag = (unsigned short*)smem;                  // 128 KB
        unsigned short* houts = (unsigned short*)(smem + 4 * 32 * 512 * 2);
        const int l = threadIdx.x;
        const int role = (bid < 16) ? 0 : 1;
        const int blk = role == 0 ? bid : bid - 16;
        const int d0 = role == 0 ? blk * 32 : blk * 16;
        const int r16 = l & 15;
        const int q = (l >> 4) & 3;
        const int ksub = q * 8;
        const int b0 = q * 4;

        if (l < 64) {
            if (role == 0) {
                // 8 tiles: gate g = ti>>1, dim-half = ti&1; 16 kt each
                for (int ti = 0; ti < 8; ++ti) {
                    int j = (ti >> 1) * 512 + d0 + (ti & 1) * 16 + r16;
                    for (int kt = 0; kt < 16; ++kt) {
                        const float* src = Whh0 + (size_t)j * DD + kt * 32 + ksub;
                        float4 x = *(const float4*)src;
                        float4 y = *(const float4*)(src + 4);
                        bf16x8 w;
                        w[0] = f2bf(x.x); w[1] = f2bf(x.y); w[2] = f2bf(x.z); w[3] = f2bf(x.w);
                        w[4] = f2bf(y.x); w[5] = f2bf(y.y); w[6] = f2bf(y.z); w[7] = f2bf(y.w);
                        *(bf16x8*)&wfrag[((ti * 16 + kt) * 64 + l) * 8] = w;
                    }
                }
            } else {
                for (int tile = 0; tile < 4; ++tile) {
                    int j = tile * 512 + d0 + r16;
                    for (int kt = 0; kt < 32; ++kt) {
                        const float* src = (kt < 16)
                            ? Wih1 + (size_t)j * DD + kt * 32 + ksub
                            : Whh1 + (size_t)j * DD + (kt - 16) * 32 + ksub;
                        float4 x = *(const float4*)src;
                        float4 y = *(const float4*)(src + 4);
                        bf16x8 w;
                        w[0] = f2bf(x.x); w[1] = f2bf(x.y); w[2] = f2bf(x.z); w[3] = f2bf(x.w);
                        w[4] = f2bf(y.x); w[5] = f2bf(y.y); w[6] = f2bf(y.z); w[7] = f2bf(y.w);
                        *(bf16x8*)&wfrag[((tile * 32 + kt) * 64 + l) * 8] = w;
                    }
                }
            }
        }
        __syncthreads();

        if (l >= 64) {
            // observer wave (layer-1 blocks only); other extra waves exit
            if (role == 1 && l < 128) {
                const int lw = l - 64;
                const int ob = lw >> 2;
                const int oseg = lw & 3;
                const char* base = (const char*)(outsb + ((size_t)ob * TT) * DD + d0 + oseg * 4);
                for (int t = 0; t < TT; ++t) {
                    const void* addr = base + (size_t)t * DD * 2;
                    for (;;) {
                        unsigned long long v;
                        asm volatile("global_load_dwordx2 %0, %1, off sc0 sc1\n\ts_waitcnt vmcnt(0)"
                                     : "=v"(v) : "v"(addr) : "memory");
                        if (!__any((v & SENTMASK64) != 0)) break;
                        __builtin_amdgcn_s_sleep(2);
                    }
                    if (lw == 0) {
                        int tv = t + 1;
                        asm volatile("global_store_dword %0, %1, off sc0 sc1"
                                     :: "v"(ep1 + blk * 16), "v"(tv) : "memory");
                    }
                }
            }
            return;
        }

        lf_u xf[16];

        if (role == 0) {
            float cst[8] = {0.f, 0.f, 0.f, 0.f, 0.f, 0.f, 0.f, 0.f};
            for (int t = 0; t < TT; ++t) {
                // Gx prefetch (8 tiles x 4 rr; overlaps the poll via vmcnt batching)
                float gx[8][4];
                #pragma unroll
                for (int ti = 0; ti < 8; ++ti)
                    #pragma unroll
                    for (int rr = 0; rr < 4; ++rr)
                        gx[ti][rr] = Gx[((size_t)(b0 + rr) * TT + t) * G4
                                        + (ti >> 1) * 512 + d0 + (ti & 1) * 16 + r16];

                const char* xb = (const char*)(h0hist + (size_t)t * (BB * DD) + r16 * DD) + q * 16;
                poll16sc(xb, xf);

                f32x4 acc[8];
                #pragma unroll
                for (int ti = 0; ti < 8; ++ti) acc[ti] = (f32x4)0.f;
                #pragma unroll
                for (int kt = 0; kt < 16; ++kt) {
                    #pragma unroll
                    for (int ti = 0; ti < 8; ++ti) {
                        bf16x8 wf = *(const bf16x8*)&wfrag[((ti * 16 + kt) * 64 + l) * 8];
                        acc[ti] = __builtin_amdgcn_mfma_f32_16x16x32_bf16(xf[kt].v, wf, acc[ti], 0, 0, 0);
                    }
                }
                #pragma unroll
                for (int rr = 0; rr < 4; ++rr) {
                    #pragma unroll
                    for (int hf_ = 0; hf_ < 2; ++hf_) {
                        float gi = acc[0 + hf_][rr] + gx[0 + hf_][rr];
                        float gf = acc[2 + hf_][rr] + gx[2 + hf_][rr];
                        float gg = acc[4 + hf_][rr] + gx[4 + hf_][rr];
                        float go = acc[6 + hf_][rr] + gx[6 + hf_][rr];
                        float cn = sigmoidf_(gf) * cst[rr * 2 + hf_] + sigmoidf_(gi) * tanhf(gg);
                        float hn = sigmoidf_(go) * tanhf(cn);
                        cst[rr * 2 + hf_] = cn;
                        houts[(b0 + rr) * 32 + hf_ * 16 + r16] = f2bf(hn);
                    }
                }
                asm volatile("" ::: "memory");
                {
                    const unsigned short* hp = &houts[(l >> 2) * 32 + (l & 3) * 8];
                    unsigned long long lo =  (unsigned long long)hp[0]
                                          | ((unsigned long long)hp[1] << 16)
                                          | ((unsigned long long)hp[2] << 32)
                                          | ((unsigned long long)hp[3] << 48);
                    unsigned long long hi =  (unsigned long long)hp[4]
                                          | ((unsigned long long)hp[5] << 16)
                                          | ((unsigned long long)hp[6] << 32)
                                          | ((unsigned long long)hp[7] << 48);
                    store16sc(h0hist + (size_t)(t + 1) * (BB * DD) + (l >> 2) * DD + d0 + (l & 3) * 8,
                              lo, hi);
                }
            }
        } else {
            const int srow = (l >> 2) & 15;
            const int sseg = l & 3;
            float cst[4] = {0.f, 0.f, 0.f, 0.f};
            lf_u hf[16];
            float bin[4];
            #pragma unroll
            for (int ni = 0; ni < 4; ++ni)
                bin[ni] = bih1[ni * 512 + d0 + r16] + bhh1[ni * 512 + d0 + r16];
            for (int t = 0; t < TT; ++t) {
                const char* xb = (const char*)(h0hist + (size_t)(t + 1) * (BB * DD) + r16 * DD) + q * 16;
                poll16sc(xb, xf);

                f32x4 acc[4];
                #pragma unroll
                for (int ni = 0; ni < 4; ++ni)
                    acc[ni] = (f32x4){bin[ni], bin[ni], bin[ni], bin[ni]};
                #pragma unroll
                for (int kt = 0; kt < 16; ++kt) {
                    #pragma unroll
                    for (int ni = 0; ni < 4; ++ni) {
                        bf16x8 wf = *(const bf16x8*)&wfrag[((ni * 32 + kt) * 64 + l) * 8];
                        acc[ni] = __builtin_amdgcn_mfma_f32_16x16x32_bf16(xf[kt].v, wf, acc[ni], 0, 0, 0);
                    }
                }
                const char* hb = (t == 0)
                    ? (const char*)(zbuf + r16 * DD) + q * 16
                    : (const char*)(outsb + ((size_t)r16 * TT + (t - 1)) * DD) + q * 16;
                poll16sc(hb, hf);
                #pragma unroll
                for (int kt = 0; kt < 16; ++kt) {
                    #pragma unroll
                    for (int ni = 0; ni < 4; ++ni) {
                        bf16x8 wf = *(const bf16x8*)&wfrag[((ni * 32 + 16 + kt) * 64 + l) * 8];
                        acc[ni] = __builtin_amdgcn_mfma_f32_16x16x32_bf16(hf[kt].v, wf, acc[ni], 0, 0, 0);
                    }
                }
                #pragma unroll
                for (int rr = 0; rr < 4; ++rr) {
                    float gi = acc[0][rr], gf = acc[1][rr], gg = acc[2][rr], go = acc[3][rr];
                    float cn = sigmoidf_(gf) * cst[rr] + sigmoidf_(gi) * tanhf(gg);
                    float hn = sigmoidf_(go) * tanhf(cn);
                    cst[rr] = cn;
                    houts[(b0 + rr) * 16 + r16] = f2bf(hn);
                }
                asm volatile("" ::: "memory");
                {
                    const unsigned short* hp = &houts[srow * 16 + sseg * 4];
                    unsigned long long w8 =  (unsigned long long)hp[0]
                                          | ((unsigned long long)hp[1] << 16)
                                          | ((unsigned long long)hp[2] << 32)
                                          | ((unsigned long long)hp[3] << 48);
                    store8sc(outsb + ((size_t)srow * TT + t) * DD + d0 + sseg * 4, w8);
                }
            }
        }
    } else if (bid >= 64 && bid < 64 + NWORK) {
        // ================= persistent out-GEMM worker role =================
        unsigned short* Alds = (unsigned short*)smem;                    // 8 KB
        unsigned short* Blds = (unsigned short*)(smem + 8192);           // 8 KB
        const int tid = threadIdx.x, lane = tid & 63, w = tid >> 6;
        const int wr = w >> 1, wc = w & 1;
        const int wid = bid - 64;

        // ---- Wout -> bf16 (write-through so all XCDs see it) ----
        for (size_t i = (size_t)wid * 256 + tid; i < (size_t)VV * DD / 4;
             i += (size_t)NWORK * 256) {
            float4 v = ((const float4*)Wout)[i];
            unsigned long long pk =  (unsigned long long)f2bf(v.x)
                                  | ((unsigned long long)f2bf(v.y) << 16)
                                  | ((unsigned long long)f2bf(v.z) << 32)
                                  | ((unsigned long long)f2bf(v.w) << 48);
            store8sc(Woutb + i * 4, pk);
        }
        asm volatile("s_waitcnt vmcnt(0)" ::: "memory");
        if (tid == 0) {
            atomicAdd(wdone, 1);
            for (;;) {
                int v;
                asm volatile("global_load_dword %0, %1, off sc0 sc1\n\ts_waitcnt vmcnt(0)"
                             : "=v"(v) : "v"(wdone) : "memory");
                if (v >= NWORK) break;
                __builtin_amdgcn_s_sleep(8);
            }
        }
        __syncthreads();

        for (;;) {
            if (tid == 0) idSh = atomicAdd(tick, 1);
            __syncthreads();
            int id = idSh;
            if (id >= NTILES) break;

            int chunk = id / 500;
            int rem   = id % 500;
            int bg    = rem / 250;
            int nt    = rem % 250;
            int t0 = chunk * 16;
            int n0 = nt * 128;
            int target = t0 + 16;

            for (;;) {
                int v;
                asm volatile("global_load_dword %0, %1, off sc0 sc1\n\ts_waitcnt vmcnt(0)"
                             : "=v"(v) : "v"(ep1 + (lane & 31) * 16) : "memory");
                if (__all(v >= target)) break;
                __builtin_amdgcn_s_sleep(32);
            }

            f32x4 acc[4][4];
            #pragma unroll
            for (int i = 0; i < 4; i++)
                #pragma unroll
                for (int j = 0; j < 4; j++) acc[i][j] = (f32x4)0.f;

            for (int ks = 0; ks < DD; ks += 32) {
                #pragma unroll
                for (int c = 0; c < 2; ++c) {
                    int f = (tid + c * 256) * 16;
                    int row = f >> 6;
                    int inb = f & 63;
                    int bb = bg * 8 + (row >> 4);
                    int tt = t0 + (row & 15);
                    const char* gA = (const char*)outsb +
                        (((size_t)bb * TT + tt) * DD + ks) * 2 + inb;
                    __builtin_amdgcn_global_load_lds(
                        (const __attribute__((address_space(1))) void*)gA,
                        (__attribute__((address_space(3))) void*)((char*)Alds + f), 16, 0, 0);
                    const char* gB = (const char*)Woutb +
                        (((size_t)(n0 + row)) * DD + ks) * 2 + inb;
                    __builtin_amdgcn_global_load_lds(
                        (const __attribute__((address_space(1))) void*)gB,
                        (__attribute__((address_space(3))) void*)((char*)Blds + f), 16, 0, 0);
                }
                __syncthreads();
                bf16x8 af[4], bfr[4];
                int r = lane & 15, ko = (lane >> 4) * 8;
                #pragma unroll
                for (int mi = 0; mi < 4; ++mi)
                    af[mi] = *(const bf16x8*)&Alds[(wr * 64 + mi * 16 + r) * 32 + ko];
                #pragma unroll
                for (int ni = 0; ni < 4; ++ni)
                    bfr[ni] = *(const bf16x8*)&Blds[(wc * 64 + ni * 16 + r) * 32 + ko];
                #pragma unroll
                for (int mi = 0; mi < 4; ++mi)
                    #pragma unroll
                    for (int ni = 0; ni < 4; ++ni)
                        acc[mi][ni] = __builtin_amdgcn_mfma_f32_16x16x32_bf16(af[mi], bfr[ni], acc[mi][ni], 0, 0, 0);
                __syncthreads();
            }
            int cr = (lane >> 4) * 4, cc = lane & 15;
            #pragma unroll
            for (int mi = 0; mi < 4; ++mi) {
                #pragma unroll
                for (int ni = 0; ni < 4; ++ni) {
                    int col = n0 + wc * 64 + ni * 16 + cc;
                    #pragma unroll
                    for (int rr = 0; rr < 4; ++rr) {
                        int rloc = wr * 64 + mi * 16 + cr + rr;
                        int bb = bg * 8 + (rloc >> 4);
                        int tt = t0 + (rloc & 15);
                        out[((size_t)bb * TT + tt) * VV + col] = acc[mi][ni][rr] + bout[col];
                    }
                }
            }
        }
    }
}

extern "C" void kernel_launch(void* const* d_in, const int* in_sizes, int n_in,
                              void* d_out, int out_size, void* d_ws, size_t ws_size,
                              hipStream_t stream) {
    const int*   tok   = (const int*)  d_in[0];
    const float* enc   = (const float*)d_in[1];
    const float* embed = (const float*)d_in[2];
    const float* Wih0  = (const float*)d_in[3];
    const float* Whh0  = (const float*)d_in[4];
    const float* bih0  = (const float*)d_in[5];
    const float* bhh0  = (const float*)d_in[6];
    const float* Wih1  = (const float*)d_in[7];
    const float* Whh1  = (const float*)d_in[8];
    const float* bih1  = (const float*)d_in[9];
    const float* bhh1  = (const float*)d_in[10];
    const float* Wout  = (const float*)d_in[11];
    const float* bout  = (const float*)d_in[12];
    float* out = (float*)d_out;

    char* ws = (char*)d_ws;
    size_t off = 0;
    auto alloc = [&](size_t bytes) -> char* {
        char* p = ws + off; off += (bytes + 255) & ~(size_t)255; return p;
    };
    unsigned short* Xb     = (unsigned short*)alloc((size_t)BB * TT * DD * 2);
    unsigned short* Wih0xb = (unsigned short*)alloc((size_t)G4 * DD * 2);
    unsigned short* Woutb  = (unsigned short*)alloc((size_t)VV * DD * 2);
    float*          et     = (float*)alloc((size_t)BB * G4 * sizeof(float));
    float*          Gx     = (float*)alloc((size_t)BB * TT * G4 * sizeof(float));
    unsigned short* outsb  = (unsigned short*)alloc((size_t)BB * TT * DD * 2);
    unsigned short* h0hist = (unsigned short*)alloc((size_t)(TT + 1) * BB * DD * 2);
    unsigned short* zbuf   = (unsigned short*)alloc((size_t)BB * DD * 2);
    int*            ep1    = (int*)alloc(32 * 16 * sizeof(int));
    int*            tick   = (int*)alloc(64 * sizeof(int));
    int*            wdone  = (int*)alloc(64 * sizeof(int));

    // sentinel init: slot 0 of h0hist + zbuf = zeros (valid), everything else 0xFF (invalid)
    hipMemsetAsync(h0hist, 0, (size_t)BB * DD * 2, stream);
    hipMemsetAsync(h0hist + (size_t)BB * DD, 0xFF, (size_t)TT * BB * DD * 2, stream);
    hipMemsetAsync(outsb, 0xFF, (size_t)BB * TT * DD * 2, stream);
    hipMemsetAsync(zbuf, 0, (size_t)BB * DD * 2, stream);
    hipMemsetAsync(ep1, 0, 32 * 16 * sizeof(int), stream);
    hipMemsetAsync(tick, 0, 64 * sizeof(int), stream);
    hipMemsetAsync(wdone, 0, 64 * sizeof(int), stream);

    k_prep<<<BB * TT + 1024 + 128, 256, 0, stream>>>(
        tok, embed, Xb, Wih0, Wih0xb, enc, bih0, bhh0, et);

    dim3 g1(BB * TT / 128, G4 / 128);
    k_gemm0<<<g1, 256, 0, stream>>>(Xb, Wih0xb, Gx, et, BB * TT, G4, DD);

    k_mega<<<256, 256, 0, stream>>>(Gx, Whh0, Wih1, Whh1, bih1, bhh1,
                                    h0hist, outsb, zbuf,
                                    Wout, Woutb, bout, out, ep1, tick, wdone);
}

// Round 16
// 1520.288 us; speedup vs baseline: 1.2543x; 1.2543x over previous
//
#include <hip/hip_runtime.h>
#include <hip/hip_bf16.h>
#include <math.h>

#define BB 16
#define TT 256
#define DD 512
#define EE 512
#define VV 32000
#define G4 2048   // 4*D
#define NWORK 192
#define NTILES (16 * 2 * 250)   // 16 t-chunks x 2 b-groups x 250 n-tiles

typedef __attribute__((ext_vector_type(4))) float f32x4;
typedef __attribute__((ext_vector_type(8))) short bf16x8;
typedef __attribute__((ext_vector_type(4))) unsigned u32x4;

union lf_u { u32x4 q; bf16x8 v; };

#define SENTMASK32 0x40004000u               // bit14 per bf16 halfword
#define SENTMASK64 0x4000400040004000ULL

__device__ __forceinline__ unsigned short f2bf(float x) {
    unsigned u = __float_as_uint(x);
    unsigned r = (u + 0x7FFFu + ((u >> 16) & 1u)) >> 16;
    return (unsigned short)r;
}

__device__ __forceinline__ float sigmoidf_(float x) { return 1.0f / (1.0f + expf(-x)); }

// ---------------- fused prefix: gather + Wih0x cvt + enc_term ----------------
__global__ __launch_bounds__(256) void k_prep(
        const int* __restrict__ tok, const float* __restrict__ embed,
        unsigned short* __restrict__ Xb,
        const float* __restrict__ Wih0, unsigned short* __restrict__ Wih0xb,
        const float* __restrict__ enc, const float* __restrict__ bih0,
        const float* __restrict__ bhh0, float* __restrict__ et) {
    __shared__ float es[EE];
    const int blk = blockIdx.x;
    const int tid = threadIdx.x;
    if (blk < BB * TT) {
        int tk = tok[blk];
        const float* src = embed + (size_t)tk * DD;
        int i = tid * 2;
        float vx = 0.f, vy = 0.f;
        if (tk != 0) { float2 v = *(const float2*)&src[i]; vx = v.x; vy = v.y; }
        ushort2 o; o.x = f2bf(vx); o.y = f2bf(vy);
        *(ushort2*)&Xb[(size_t)blk * DD + i] = o;
    } else if (blk < BB * TT + 1024) {
        int i = (blk - BB * TT) * 256 + tid;
        int j = i >> 7;
        int k4 = (i & 127) << 2;
        float4 v = *(const float4*)&Wih0[(size_t)j * (EE + DD) + k4];
        ushort4 o; o.x = f2bf(v.x); o.y = f2bf(v.y); o.z = f2bf(v.z); o.w = f2bf(v.w);
        *(ushort4*)&Wih0xb[(size_t)j * DD + k4] = o;
    } else {
        int bidx = blk - (BB * TT + 1024);
        int b = bidx >> 3, jc = bidx & 7;
        int lane = tid & 63, w = tid >> 6;
        if (tid < EE / 4) *(float4*)&es[tid * 4] = *(const float4*)&enc[b * EE + tid * 4];
        __syncthreads();
        float4 e0 = *(const float4*)&es[lane * 4];
        float4 e1 = *(const float4*)&es[256 + lane * 4];
        for (int o = 0; o < 64; ++o) {
            int j = jc * 256 + w * 64 + o;
            const float4* Wr = (const float4*)&Wih0[(size_t)j * (EE + DD) + DD];
            float4 w0 = Wr[lane], w1 = Wr[64 + lane];
            float s = w0.x*e0.x + w0.y*e0.y + w0.z*e0.z + w0.w*e0.w
                    + w1.x*e1.x + w1.y*e1.y + w1.z*e1.z + w1.w*e1.w;
            #pragma unroll
            for (int off = 32; off; off >>= 1) s += __shfl_xor(s, off);
            if (lane == 0) et[b * G4 + j] = s + bih0[j] + bhh0[j];
        }
    }
}

// ---------------- bf16 MFMA GEMM (Gx pre-GEMM only), C = A@B^T + enc_term ----------------
__global__ __launch_bounds__(256) void k_gemm0(
        const unsigned short* __restrict__ A, const unsigned short* __restrict__ Bm,
        float* __restrict__ C, const float* __restrict__ extra,
        int M, int N, int K) {
    __shared__ __align__(16) unsigned short Alds[128 * 32];
    __shared__ __align__(16) unsigned short Blds[128 * 32];
    int tid = threadIdx.x, lane = tid & 63, w = tid >> 6;
    int wr = w >> 1, wc = w & 1;
    int nwgx = gridDim.x;
    int nwg = nwgx * gridDim.y;
    int lin = blockIdx.y * nwgx + blockIdx.x;
    int cpx = nwg >> 3;
    lin = (lin & 7) * cpx + (lin >> 3);
    int m0 = (lin % nwgx) * 128, n0 = (lin / nwgx) * 128;
    f32x4 acc[4][4];
    #pragma unroll
    for (int i = 0; i < 4; i++)
        #pragma unroll
        for (int j = 0; j < 4; j++) acc[i][j] = (f32x4)0.f;

    const char* Abase = (const char*)A;
    const char* Bbase = (const char*)Bm;
    for (int ks = 0; ks < K; ks += 32) {
        #pragma unroll
        for (int c = 0; c < 2; ++c) {
            int f = (tid + c * 256) * 16;
            int row = f >> 6;
            int inb = f & 63;
            const char* gA = Abase + (((size_t)(m0 + row) * K + ks) * 2 + inb);
            __builtin_amdgcn_global_load_lds(
                (const __attribute__((address_space(1))) void*)gA,
                (__attribute__((address_space(3))) void*)((char*)Alds + f), 16, 0, 0);
            const char* gB = Bbase + (((size_t)(n0 + row) * K + ks) * 2 + inb);
            __builtin_amdgcn_global_load_lds(
                (const __attribute__((address_space(1))) void*)gB,
                (__attribute__((address_space(3))) void*)((char*)Blds + f), 16, 0, 0);
        }
        __syncthreads();
        bf16x8 af[4], bfr[4];
        int r = lane & 15, ko = (lane >> 4) * 8;
        #pragma unroll
        for (int mi = 0; mi < 4; ++mi)
            af[mi] = *(const bf16x8*)&Alds[(wr * 64 + mi * 16 + r) * 32 + ko];
        #pragma unroll
        for (int ni = 0; ni < 4; ++ni)
            bfr[ni] = *(const bf16x8*)&Blds[(wc * 64 + ni * 16 + r) * 32 + ko];
        #pragma unroll
        for (int mi = 0; mi < 4; ++mi)
            #pragma unroll
            for (int ni = 0; ni < 4; ++ni)
                acc[mi][ni] = __builtin_amdgcn_mfma_f32_16x16x32_bf16(af[mi], bfr[ni], acc[mi][ni], 0, 0, 0);
        __syncthreads();
    }
    int cr = (lane >> 4) * 4, cc = lane & 15;
    #pragma unroll
    for (int mi = 0; mi < 4; ++mi) {
        #pragma unroll
        for (int ni = 0; ni < 4; ++ni) {
            int col = n0 + wc * 64 + ni * 16 + cc;
            #pragma unroll
            for (int rr = 0; rr < 4; ++rr) {
                int rowg = m0 + wr * 64 + mi * 16 + cr + rr;
                C[(size_t)rowg * N + col] = acc[mi][ni][rr] + extra[(rowg >> 8) * G4 + col];
            }
        }
    }
}

// ---------------- fully-coherent (sc0 sc1) batched 16x16B load ----------------
__device__ __forceinline__ void load16sc(const void* base, lf_u* o) {
    asm volatile(
        "global_load_dwordx4 %0, %16, off sc0 sc1\n\t"
        "global_load_dwordx4 %1, %16, off offset:64 sc0 sc1\n\t"
        "global_load_dwordx4 %2, %16, off offset:128 sc0 sc1\n\t"
        "global_load_dwordx4 %3, %16, off offset:192 sc0 sc1\n\t"
        "global_load_dwordx4 %4, %16, off offset:256 sc0 sc1\n\t"
        "global_load_dwordx4 %5, %16, off offset:320 sc0 sc1\n\t"
        "global_load_dwordx4 %6, %16, off offset:384 sc0 sc1\n\t"
        "global_load_dwordx4 %7, %16, off offset:448 sc0 sc1\n\t"
        "global_load_dwordx4 %8, %16, off offset:512 sc0 sc1\n\t"
        "global_load_dwordx4 %9, %16, off offset:576 sc0 sc1\n\t"
        "global_load_dwordx4 %10, %16, off offset:640 sc0 sc1\n\t"
        "global_load_dwordx4 %11, %16, off offset:704 sc0 sc1\n\t"
        "global_load_dwordx4 %12, %16, off offset:768 sc0 sc1\n\t"
        "global_load_dwordx4 %13, %16, off offset:832 sc0 sc1\n\t"
        "global_load_dwordx4 %14, %16, off offset:896 sc0 sc1\n\t"
        "global_load_dwordx4 %15, %16, off offset:960 sc0 sc1\n\t"
        "s_waitcnt vmcnt(0)"
        : "=&v"(o[0].q), "=&v"(o[1].q), "=&v"(o[2].q), "=&v"(o[3].q),
          "=&v"(o[4].q), "=&v"(o[5].q), "=&v"(o[6].q), "=&v"(o[7].q),
          "=&v"(o[8].q), "=&v"(o[9].q), "=&v"(o[10].q), "=&v"(o[11].q),
          "=&v"(o[12].q), "=&v"(o[13].q), "=&v"(o[14].q), "=&v"(o[15].q)
        : "v"(base)
        : "memory");
}

__device__ __forceinline__ void poll16sc(const void* base, lf_u* o) {
    for (;;) {
        load16sc(base, o);
        unsigned bad = 0;
        #pragma unroll
        for (int kt = 0; kt < 16; ++kt)
            bad |= (o[kt].q.x | o[kt].q.y | o[kt].q.z | o[kt].q.w);
        if (!__any((bad & SENTMASK32) != 0)) return;
    }
}

__device__ __forceinline__ void store8sc(void* addr, unsigned long long v) {
    asm volatile("global_store_dwordx2 %0, %1, off sc0 sc1"
                 :: "v"(addr), "v"(v) : "memory");
}

// ---------------- mega kernel: persistent recurrence + observer flags + out-GEMM ----------------
// 256 blocks x 256 threads, 1 block/CU (co-resident).
// Blocks 0..31: layer 0 (wave 0, r11-proven loop, no flags).
// Blocks 32..63: layer 1. Wave 0 = r11-proven loop (no drain). Wave 1 = observer:
//   verifies own block's step-t outsb slice at the coherent point, then publishes ep1.
// Blocks 64..255: workers (convert Wout->bf16, worker barrier, ticket-claim out-tiles).
// Recurrence never waits on workers/observer: no deadlock path.
__global__ __launch_bounds__(256) void k_mega(
        const float* __restrict__ Gx,
        const float* __restrict__ Whh0,
        const float* __restrict__ Wih1, const float* __restrict__ Whh1,
        const float* __restrict__ bih1, const float* __restrict__ bhh1,
        unsigned short* h0hist, unsigned short* outsb,
        const unsigned short* zbuf,
        const float* __restrict__ Wout, unsigned short* Woutb,
        const float* __restrict__ bout, float* __restrict__ out,
        int* ep1, int* tick, int* wdone) {
    __shared__ __align__(16) unsigned char smem[4 * 32 * 512 * 2 + 512];
    __shared__ int idSh;
    const int bid = blockIdx.x;

    if (bid < 64) {
        // ================= recurrence role =================
        unsigned short* wfrag = (unsigned short*)smem;                  // 128 KB
        unsigned short* houts = (unsigned short*)(smem + 4 * 32 * 512 * 2);
        const int l = threadIdx.x;
        const int role = bid >> 5;
        const int blk = bid & 31;
        const int d0 = blk * 16;
        const int r16 = l & 15;
        const int q = (l >> 4) & 3;
        const int ksub = q * 8;
        const int b0 = q * 4;
        const int srow = (l >> 2) & 15;
        const int sseg = l & 3;

        const int nkt = role ? 32 : 16;
        if (l < 64) {
            for (int tile = 0; tile < 4; ++tile) {
                int j = tile * 512 + d0 + r16;
                for (int kt = 0; kt < nkt; ++kt) {
                    const float* src;
                    if (role == 0)    src = Whh0 + (size_t)j * DD + kt * 32 + ksub;
                    else if (kt < 16) src = Wih1 + (size_t)j * DD + kt * 32 + ksub;
                    else              src = Whh1 + (size_t)j * DD + (kt - 16) * 32 + ksub;
                    float4 x = *(const float4*)src;
                    float4 y = *(const float4*)(src + 4);
                    bf16x8 w;
                    w[0] = f2bf(x.x); w[1] = f2bf(x.y); w[2] = f2bf(x.z); w[3] = f2bf(x.w);
                    w[4] = f2bf(y.x); w[5] = f2bf(y.y); w[6] = f2bf(y.z); w[7] = f2bf(y.w);
                    *(bf16x8*)&wfrag[((tile * 32 + kt) * 64 + l) * 8] = w;
                }
            }
        }
        __syncthreads();

        if (l >= 64) {
            // observer wave (layer-1 blocks only); other extra waves exit
            if (role == 1 && l < 128) {
                const int lw = l - 64;
                const int ob = lw >> 2;
                const int oseg = lw & 3;
                const char* base = (const char*)(outsb + ((size_t)ob * TT) * DD + d0 + oseg * 4);
                for (int t = 0; t < TT; ++t) {
                    const void* addr = base + (size_t)t * DD * 2;
                    for (;;) {
                        unsigned long long v;
                        asm volatile("global_load_dwordx2 %0, %1, off sc0 sc1\n\ts_waitcnt vmcnt(0)"
                                     : "=v"(v) : "v"(addr) : "memory");
                        if (!__any((v & SENTMASK64) != 0)) break;
                        __builtin_amdgcn_s_sleep(2);
                    }
                    if (lw == 0) {
                        int tv = t + 1;
                        asm volatile("global_store_dword %0, %1, off sc0 sc1"
                                     :: "v"(ep1 + blk * 16), "v"(tv) : "memory");
                    }
                }
            }
            return;
        }

        float cst[4] = {0.f, 0.f, 0.f, 0.f};
        lf_u xf[16];

        if (role == 0) {
            for (int t = 0; t < TT; ++t) {
                float gx[4][4];
                #pragma unroll
                for (int ni = 0; ni < 4; ++ni)
                    #pragma unroll
                    for (int rr = 0; rr < 4; ++rr)
                        gx[ni][rr] = Gx[((size_t)(b0 + rr) * TT + t) * G4 + ni * 512 + d0 + r16];

                const char* xb = (const char*)(h0hist + (size_t)t * (BB * DD) + r16 * DD) + q * 16;
                poll16sc(xb, xf);

                f32x4 acc[4];
                #pragma unroll
                for (int ni = 0; ni < 4; ++ni) acc[ni] = (f32x4)0.f;
                #pragma unroll
                for (int kt = 0; kt < 16; ++kt) {
                    #pragma unroll
                    for (int ni = 0; ni < 4; ++ni) {
                        bf16x8 wf = *(const bf16x8*)&wfrag[((ni * 32 + kt) * 64 + l) * 8];
                        acc[ni] = __builtin_amdgcn_mfma_f32_16x16x32_bf16(xf[kt].v, wf, acc[ni], 0, 0, 0);
                    }
                }
                #pragma unroll
                for (int rr = 0; rr < 4; ++rr) {
                    float gi = acc[0][rr] + gx[0][rr], gf = acc[1][rr] + gx[1][rr];
                    float gg = acc[2][rr] + gx[2][rr], go = acc[3][rr] + gx[3][rr];
                    float cn = sigmoidf_(gf) * cst[rr] + sigmoidf_(gi) * tanhf(gg);
                    float hn = sigmoidf_(go) * tanhf(cn);
                    cst[rr] = cn;
                    houts[(b0 + rr) * 16 + r16] = f2bf(hn);
                }
                asm volatile("" ::: "memory");
                {
                    const unsigned short* hp = &houts[srow * 16 + sseg * 4];
                    unsigned long long w8 =  (unsigned long long)hp[0]
                                          | ((unsigned long long)hp[1] << 16)
                                          | ((unsigned long long)hp[2] << 32)
                                          | ((unsigned long long)hp[3] << 48);
                    store8sc(h0hist + (size_t)(t + 1) * (BB * DD) + srow * DD + d0 + sseg * 4, w8);
                }
            }
        } else {
            lf_u hf[16];
            float bin[4];
            #pragma unroll
            for (int ni = 0; ni < 4; ++ni)
                bin[ni] = bih1[ni * 512 + d0 + r16] + bhh1[ni * 512 + d0 + r16];
            for (int t = 0; t < TT; ++t) {
                const char* xb = (const char*)(h0hist + (size_t)(t + 1) * (BB * DD) + r16 * DD) + q * 16;
                poll16sc(xb, xf);

                f32x4 acc[4];
                #pragma unroll
                for (int ni = 0; ni < 4; ++ni)
                    acc[ni] = (f32x4){bin[ni], bin[ni], bin[ni], bin[ni]};
                #pragma unroll
                for (int kt = 0; kt < 16; ++kt) {
                    #pragma unroll
                    for (int ni = 0; ni < 4; ++ni) {
                        bf16x8 wf = *(const bf16x8*)&wfrag[((ni * 32 + kt) * 64 + l) * 8];
                        acc[ni] = __builtin_amdgcn_mfma_f32_16x16x32_bf16(xf[kt].v, wf, acc[ni], 0, 0, 0);
                    }
                }
                const char* hb = (t == 0)
                    ? (const char*)(zbuf + r16 * DD) + q * 16
                    : (const char*)(outsb + ((size_t)r16 * TT + (t - 1)) * DD) + q * 16;
                poll16sc(hb, hf);
                #pragma unroll
                for (int kt = 0; kt < 16; ++kt) {
                    #pragma unroll
                    for (int ni = 0; ni < 4; ++ni) {
                        bf16x8 wf = *(const bf16x8*)&wfrag[((ni * 32 + 16 + kt) * 64 + l) * 8];
                        acc[ni] = __builtin_amdgcn_mfma_f32_16x16x32_bf16(hf[kt].v, wf, acc[ni], 0, 0, 0);
                    }
                }
                #pragma unroll
                for (int rr = 0; rr < 4; ++rr) {
                    float gi = acc[0][rr], gf = acc[1][rr], gg = acc[2][rr], go = acc[3][rr];
                    float cn = sigmoidf_(gf) * cst[rr] + sigmoidf_(gi) * tanhf(gg);
                    float hn = sigmoidf_(go) * tanhf(cn);
                    cst[rr] = cn;
                    houts[(b0 + rr) * 16 + r16] = f2bf(hn);
                }
                asm volatile("" ::: "memory");
                {
                    const unsigned short* hp = &houts[srow * 16 + sseg * 4];
                    unsigned long long w8 =  (unsigned long long)hp[0]
                                          | ((unsigned long long)hp[1] << 16)
                                          | ((unsigned long long)hp[2] << 32)
                                          | ((unsigned long long)hp[3] << 48);
                    store8sc(outsb + ((size_t)srow * TT + t) * DD + d0 + sseg * 4, w8);
                }
            }
        }
    } else {
        // ================= persistent out-GEMM worker role =================
        unsigned short* Alds = (unsigned short*)smem;                    // 8 KB
        unsigned short* Blds = (unsigned short*)(smem + 8192);           // 8 KB
        const int tid = threadIdx.x, lane = tid & 63, w = tid >> 6;
        const int wr = w >> 1, wc = w & 1;
        const int wid = bid - 64;

        // ---- Wout -> bf16 (write-through so all XCDs see it) ----
        for (size_t i = (size_t)wid * 256 + tid; i < (size_t)VV * DD / 4;
             i += (size_t)NWORK * 256) {
            float4 v = ((const float4*)Wout)[i];
            unsigned long long pk =  (unsigned long long)f2bf(v.x)
                                  | ((unsigned long long)f2bf(v.y) << 16)
                                  | ((unsigned long long)f2bf(v.z) << 32)
                                  | ((unsigned long long)f2bf(v.w) << 48);
            store8sc(Woutb + i * 4, pk);
        }
        asm volatile("s_waitcnt vmcnt(0)" ::: "memory");
        if (tid == 0) {
            atomicAdd(wdone, 1);
            for (;;) {
                int v;
                asm volatile("global_load_dword %0, %1, off sc0 sc1\n\ts_waitcnt vmcnt(0)"
                             : "=v"(v) : "v"(wdone) : "memory");
                if (v >= NWORK) break;
                __builtin_amdgcn_s_sleep(8);
            }
        }
        __syncthreads();

        for (;;) {
            if (tid == 0) idSh = atomicAdd(tick, 1);
            __syncthreads();
            int id = idSh;
            if (id >= NTILES) break;

            int chunk = id / 500;
            int rem   = id % 500;
            int bg    = rem / 250;
            int nt    = rem % 250;
            int t0 = chunk * 16;
            int n0 = nt * 128;
            int target = t0 + 16;

            for (;;) {
                int v;
                asm volatile("global_load_dword %0, %1, off sc0 sc1\n\ts_waitcnt vmcnt(0)"
                             : "=v"(v) : "v"(ep1 + (lane & 31) * 16) : "memory");
                if (__all(v >= target)) break;
                __builtin_amdgcn_s_sleep(32);
            }

            f32x4 acc[4][4];
            #pragma unroll
            for (int i = 0; i < 4; i++)
                #pragma unroll
                for (int j = 0; j < 4; j++) acc[i][j] = (f32x4)0.f;

            for (int ks = 0; ks < DD; ks += 32) {
                #pragma unroll
                for (int c = 0; c < 2; ++c) {
                    int f = (tid + c * 256) * 16;
                    int row = f >> 6;
                    int inb = f & 63;
                    int bb = bg * 8 + (row >> 4);
                    int tt = t0 + (row & 15);
                    const char* gA = (const char*)outsb +
                        (((size_t)bb * TT + tt) * DD + ks) * 2 + inb;
                    __builtin_amdgcn_global_load_lds(
                        (const __attribute__((address_space(1))) void*)gA,
                        (__attribute__((address_space(3))) void*)((char*)Alds + f), 16, 0, 0);
                    const char* gB = (const char*)Woutb +
                        (((size_t)(n0 + row)) * DD + ks) * 2 + inb;
                    __builtin_amdgcn_global_load_lds(
                        (const __attribute__((address_space(1))) void*)gB,
                        (__attribute__((address_space(3))) void*)((char*)Blds + f), 16, 0, 0);
                }
                __syncthreads();
                bf16x8 af[4], bfr[4];
                int r = lane & 15, ko = (lane >> 4) * 8;
                #pragma unroll
                for (int mi = 0; mi < 4; ++mi)
                    af[mi] = *(const bf16x8*)&Alds[(wr * 64 + mi * 16 + r) * 32 + ko];
                #pragma unroll
                for (int ni = 0; ni < 4; ++ni)
                    bfr[ni] = *(const bf16x8*)&Blds[(wc * 64 + ni * 16 + r) * 32 + ko];
                #pragma unroll
                for (int mi = 0; mi < 4; ++mi)
                    #pragma unroll
                    for (int ni = 0; ni < 4; ++ni)
                        acc[mi][ni] = __builtin_amdgcn_mfma_f32_16x16x32_bf16(af[mi], bfr[ni], acc[mi][ni], 0, 0, 0);
                __syncthreads();
            }
            int cr = (lane >> 4) * 4, cc = lane & 15;
            #pragma unroll
            for (int mi = 0; mi < 4; ++mi) {
                #pragma unroll
                for (int ni = 0; ni < 4; ++ni) {
                    int col = n0 + wc * 64 + ni * 16 + cc;
                    #pragma unroll
                    for (int rr = 0; rr < 4; ++rr) {
                        int rloc = wr * 64 + mi * 16 + cr + rr;
                        int bb = bg * 8 + (rloc >> 4);
                        int tt = t0 + (rloc & 15);
                        out[((size_t)bb * TT + tt) * VV + col] = acc[mi][ni][rr] + bout[col];
                    }
                }
            }
        }
    }
}

extern "C" void kernel_launch(void* const* d_in, const int* in_sizes, int n_in,
                              void* d_out, int out_size, void* d_ws, size_t ws_size,
                              hipStream_t stream) {
    const int*   tok   = (const int*)  d_in[0];
    const float* enc   = (const float*)d_in[1];
    const float* embed = (const float*)d_in[2];
    const float* Wih0  = (const float*)d_in[3];
    const float* Whh0  = (const float*)d_in[4];
    const float* bih0  = (const float*)d_in[5];
    const float* bhh0  = (const float*)d_in[6];
    const float* Wih1  = (const float*)d_in[7];
    const float* Whh1  = (const float*)d_in[8];
    const float* bih1  = (const float*)d_in[9];
    const float* bhh1  = (const float*)d_in[10];
    const float* Wout  = (const float*)d_in[11];
    const float* bout  = (const float*)d_in[12];
    float* out = (float*)d_out;

    char* ws = (char*)d_ws;
    size_t off = 0;
    auto alloc = [&](size_t bytes) -> char* {
        char* p = ws + off; off += (bytes + 255) & ~(size_t)255; return p;
    };
    unsigned short* Xb     = (unsigned short*)alloc((size_t)BB * TT * DD * 2);
    unsigned short* Wih0xb = (unsigned short*)alloc((size_t)G4 * DD * 2);
    unsigned short* Woutb  = (unsigned short*)alloc((size_t)VV * DD * 2);
    float*          et     = (float*)alloc((size_t)BB * G4 * sizeof(float));
    float*          Gx     = (float*)alloc((size_t)BB * TT * G4 * sizeof(float));
    unsigned short* outsb  = (unsigned short*)alloc((size_t)BB * TT * DD * 2);
    unsigned short* h0hist = (unsigned short*)alloc((size_t)(TT + 1) * BB * DD * 2);
    unsigned short* zbuf   = (unsigned short*)alloc((size_t)BB * DD * 2);
    int*            ep1    = (int*)alloc(32 * 16 * sizeof(int));
    int*            tick   = (int*)alloc(64 * sizeof(int));
    int*            wdone  = (int*)alloc(64 * sizeof(int));

    // sentinel init: slot 0 of h0hist + zbuf = zeros (valid), everything else 0xFF (invalid)
    hipMemsetAsync(h0hist, 0, (size_t)BB * DD * 2, stream);
    hipMemsetAsync(h0hist + (size_t)BB * DD, 0xFF, (size_t)TT * BB * DD * 2, stream);
    hipMemsetAsync(outsb, 0xFF, (size_t)BB * TT * DD * 2, stream);
    hipMemsetAsync(zbuf, 0, (size_t)BB * DD * 2, stream);
    hipMemsetAsync(ep1, 0, 32 * 16 * sizeof(int), stream);
    hipMemsetAsync(tick, 0, 64 * sizeof(int), stream);
    hipMemsetAsync(wdone, 0, 64 * sizeof(int), stream);

    k_prep<<<BB * TT + 1024 + 128, 256, 0, stream>>>(
        tok, embed, Xb, Wih0, Wih0xb, enc, bih0, bhh0, et);

    dim3 g1(BB * TT / 128, G4 / 128);
    k_gemm0<<<g1, 256, 0, stream>>>(Xb, Wih0xb, Gx, et, BB * TT, G4, DD);

    k_mega<<<256, 256, 0, stream>>>(Gx, Whh0, Wih1, Whh1, bih1, bhh1,
                                    h0hist, outsb, zbuf,
                                    Wout, Woutb, bout, out, ep1, tick, wdone);
}